// Round 7
// baseline (93.554 us; speedup 1.0000x reference)
//
#include <hip/hip_runtime.h>

// Chamfer via MFMA, two-pass. v2: 64 rows/wave (2 A-frags), 1-wave blocks,
// 4-way column split -> 4096 blocks for occupancy; per-(row,chunk) partial
// row-mins in ws; small combine kernel does min/sqrt/mean/atomicAdd.

typedef __attribute__((ext_vector_type(8)))  short bf16x8;
typedef __attribute__((ext_vector_type(16))) float f32x16;

constexpr int NPTS   = 8192;
constexpr int BATCH  = 4;
constexpr int CSPLIT = 4;                  // column chunks
constexpr int CCOLS  = NPTS / CSPLIT;      // 2048 cols per chunk
constexpr int RT     = 64;                 // rows per wave
constexpr int N_RT   = NPTS / RT;          // 128 row tiles per (dir,b)
constexpr int STEPS  = CCOLS / 32;         // 64 col-steps per wave

// ws: [0,1MB) targ table; [1MB,2MB) pred table; [2MB,3MB) row partials.
constexpr size_t TBL_BYTES = (size_t)BATCH * NPTS * 32;
constexpr size_t ROW_OFF   = 2 * TBL_BYTES;
// ws_row layout: [db(8)][cs(4)][NPTS] f32  (db = b*2+dir packed as z*? see below)

__device__ inline unsigned short f2bf(float x) {          // RNE f32->bf16
    unsigned u = __float_as_uint(x);
    u += 0x7FFFu + ((u >> 16) & 1u);
    return (unsigned short)(u >> 16);
}
__device__ inline float bf2f(unsigned short h) {
    return __uint_as_float(((unsigned)h) << 16);
}

// ---------------- pack both point sets into B-operand tables ----------------
__global__ __launch_bounds__(256) void pack_both(
    const float* __restrict__ pred, const float* __restrict__ targ,
    unsigned int* __restrict__ wsb) {
    int tid = blockIdx.x * 256 + threadIdx.x;          // 0..65535
    int which = tid >> 15;                             // 0: targ, 1: pred
    int r = tid & 32767;
    int b = r >> 13, m = r & (NPTS - 1);
    const float* src = which ? pred : targ;
    const float* tb = src + (size_t)b * 3 * NPTS;
    float tx = tb[m], ty = tb[NPTS + m], tz = tb[2 * NPTS + m];
    float t2 = fmaf(tx, tx, fmaf(ty, ty, tz * tz));
    unsigned short xh = f2bf(tx), yh = f2bf(ty), zh = f2bf(tz);
    unsigned short xl = f2bf(tx - bf2f(xh));
    unsigned short yl = f2bf(ty - bf2f(yh));
    unsigned short zl = f2bf(tz - bf2f(zh));
    unsigned short t2h = f2bf(t2), t2l = f2bf(t2 - bf2f(t2h));
    const unsigned short ONE = 0x3F80;
    // k: 0:1*p2h 1:1*p2l 2:t2h*1 3:t2l*1 4:txh 5:txl 6:txh 7:tyh
    //    8:tyl 9:tyh 10:tzh 11:tzl 12:tzh 13-15:0   (verified, absmax 0.0)
    unsigned int u0 = (unsigned)ONE | ((unsigned)ONE << 16);
    unsigned int u1 = (unsigned)t2h | ((unsigned)t2l << 16);
    unsigned int u2 = (unsigned)xh  | ((unsigned)xl  << 16);
    unsigned int u3 = (unsigned)xh  | ((unsigned)yh  << 16);
    unsigned int u4 = (unsigned)yl  | ((unsigned)yh  << 16);
    unsigned int u5 = (unsigned)zh  | ((unsigned)zl  << 16);
    unsigned int u6 = (unsigned)zh;
    uint4* dst = (uint4*)wsb;
    dst[(size_t)tid * 2]     = make_uint4(u0, u1, u2, u3);
    dst[(size_t)tid * 2 + 1] = make_uint4(u4, u5, u6, 0u);
}

// ---------------- main kernel ----------------
__global__ __launch_bounds__(64) void chamfer_v2(
    const float* __restrict__ pred, const float* __restrict__ targ,
    const unsigned int* __restrict__ wsb, float* __restrict__ ws_row) {
    const int lane = threadIdx.x;
    const int g    = lane >> 5;       // k-group
    const int rt   = blockIdx.x;      // 0..127 row tile
    const int cs   = blockIdx.y;      // 0..3   column chunk
    const int db   = blockIdx.z;      // 0..7 : dir = db&1, b = db>>1
    const int dir  = db & 1;
    const int b    = db >> 1;

    const float* rowsrc = dir ? targ : pred;
    const float* pb = rowsrc + (size_t)b * 3 * NPTS;

    const unsigned short ONE = 0x3F80;
    auto build_af = [&](int row) -> bf16x8 {
        float px = pb[row], py = pb[NPTS + row], pz = pb[2 * NPTS + row];
        float p2 = fmaf(px, px, fmaf(py, py, pz * pz));
        unsigned short xh = f2bf(px), yh = f2bf(py), zh = f2bf(pz);
        unsigned short xl = f2bf(px - bf2f(xh));
        unsigned short yl = f2bf(py - bf2f(yh));
        unsigned short zl = f2bf(pz - bf2f(zh));
        unsigned short p2h = f2bf(p2), p2l = f2bf(p2 - bf2f(p2h));
        unsigned short mxh = f2bf(-2.f * bf2f(xh)), mxl = f2bf(-2.f * bf2f(xl));
        unsigned short myh = f2bf(-2.f * bf2f(yh)), myl = f2bf(-2.f * bf2f(yl));
        unsigned short mzh = f2bf(-2.f * bf2f(zh)), mzl = f2bf(-2.f * bf2f(zl));
        unsigned short av[8];
        if (g == 0) {
            av[0]=p2h; av[1]=p2l; av[2]=ONE; av[3]=ONE;
            av[4]=mxh; av[5]=mxh; av[6]=mxl; av[7]=myh;
        } else {
            av[0]=myh; av[1]=myl; av[2]=mzh; av[3]=mzh;
            av[4]=mzl; av[5]=0;   av[6]=0;   av[7]=0;
        }
        bf16x8 f;
        #pragma unroll
        for (int i = 0; i < 8; ++i) f[i] = (short)av[i];
        return f;
    };

    const int r0 = rt * RT + (lane & 31);
    bf16x8 af0 = build_af(r0);
    bf16x8 af1 = build_af(r0 + 32);

    f32x16 zero;
    #pragma unroll
    for (int i = 0; i < 16; ++i) zero[i] = 0.f;

    float racc0[16], racc1[16];
    #pragma unroll
    for (int i = 0; i < 16; ++i) {
        racc0[i] = __int_as_float(0x7F800000);
        racc1[i] = __int_as_float(0x7F800000);
    }

    const char* btab = (const char*)wsb
        + (size_t)dir * TBL_BYTES
        + (size_t)b * NPTS * 32
        + (size_t)cs * CCOLS * 32
        + (size_t)(lane & 31) * 32 + (size_t)g * 16;

    auto ldg = [&](int s) -> bf16x8 {
        return *reinterpret_cast<const bf16x8*>(btab + (size_t)s * 1024);
    };
    auto proc2 = [&](bf16x8 fa, bf16x8 fb) {
        f32x16 ca = __builtin_amdgcn_mfma_f32_32x32x16_bf16(af0, fa, zero, 0, 0, 0);
        f32x16 cb = __builtin_amdgcn_mfma_f32_32x32x16_bf16(af0, fb, zero, 0, 0, 0);
        #pragma unroll
        for (int i = 0; i < 16; ++i)
            racc0[i] = fminf(fminf(racc0[i], ca[i]), cb[i]);   // v_min3_f32
        f32x16 cc = __builtin_amdgcn_mfma_f32_32x32x16_bf16(af1, fa, zero, 0, 0, 0);
        f32x16 cd = __builtin_amdgcn_mfma_f32_32x32x16_bf16(af1, fb, zero, 0, 0, 0);
        #pragma unroll
        for (int i = 0; i < 16; ++i)
            racc1[i] = fminf(fminf(racc1[i], cc[i]), cd[i]);
    };

    // 2-step groups with next-group prefetch (2 waves of cover + 4/SIMD TLP)
    bf16x8 f0 = ldg(0), f1 = ldg(1);
    for (int s = 0; s < STEPS - 2; s += 2) {
        bf16x8 n0 = ldg(s + 2), n1 = ldg(s + 3);
        proc2(f0, f1);
        f0 = n0; f1 = n1;
    }
    proc2(f0, f1);

    // ---- butterfly col-min within each 32-lane half ----
    #pragma unroll
    for (int i = 0; i < 16; ++i) {
        float v = racc0[i];
        v = fminf(v, __shfl_xor(v, 1));
        v = fminf(v, __shfl_xor(v, 2));
        v = fminf(v, __shfl_xor(v, 4));
        v = fminf(v, __shfl_xor(v, 8));
        v = fminf(v, __shfl_xor(v, 16));
        racc0[i] = v;
        float w = racc1[i];
        w = fminf(w, __shfl_xor(w, 1));
        w = fminf(w, __shfl_xor(w, 2));
        w = fminf(w, __shfl_xor(w, 4));
        w = fminf(w, __shfl_xor(w, 8));
        w = fminf(w, __shfl_xor(w, 16));
        racc1[i] = w;
    }
    if ((lane & 31) == 0) {
        float* base = ws_row + ((size_t)db * CSPLIT + cs) * NPTS + (size_t)rt * RT;
        #pragma unroll
        for (int i = 0; i < 16; ++i) {
            int r = (i & 3) + 8 * (i >> 2) + 4 * g;   // C/D row map (m74/m101)
            base[r]      = racc0[i];
            base[32 + r] = racc1[i];
        }
    }
}

// ---------------- combine: min over chunks, sqrt, mean, sum ----------------
__global__ __launch_bounds__(256) void reduce_rows(
    const float* __restrict__ ws_row, float* __restrict__ out) {
    int tid = blockIdx.x * 256 + threadIdx.x;   // 0..65535
    int db  = tid >> 13;                        // 0..7
    int row = tid & (NPTS - 1);
    const float* base = ws_row + (size_t)db * CSPLIT * NPTS + row;
    float v = base[0];
    #pragma unroll
    for (int cshift = 1; cshift < CSPLIT; ++cshift)
        v = fminf(v, base[(size_t)cshift * NPTS]);
    float d = sqrtf(fmaxf(v, 0.f)) * (1.0f / 32768.0f);
    for (int off = 32; off; off >>= 1) d += __shfl_down(d, off);
    __shared__ float wsum[4];
    if ((threadIdx.x & 63) == 0) wsum[threadIdx.x >> 6] = d;
    __syncthreads();
    if (threadIdx.x == 0) atomicAdd(out, wsum[0] + wsum[1] + wsum[2] + wsum[3]);
}

extern "C" void kernel_launch(void* const* d_in, const int* in_sizes, int n_in,
                              void* d_out, int out_size, void* d_ws, size_t ws_size,
                              hipStream_t stream) {
    const float* pred = (const float*)d_in[0];
    const float* targ = (const float*)d_in[1];
    float* out = (float*)d_out;
    char* ws = (char*)d_ws;
    unsigned int* wsb = (unsigned int*)ws;
    float* ws_row = (float*)(ws + ROW_OFF);   // 1 MB

    hipMemsetAsync(d_out, 0, sizeof(float), stream);

    pack_both<<<(2 * BATCH * NPTS) / 256, 256, 0, stream>>>(pred, targ, wsb);

    dim3 grid(N_RT, CSPLIT, 2 * BATCH);   // 128 x 4 x 8 = 4096 one-wave blocks
    chamfer_v2<<<grid, 64, 0, stream>>>(pred, targ, wsb, ws_row);

    reduce_rows<<<(2 * BATCH * NPTS) / 256, 256, 0, stream>>>(ws_row, out);
}

// Round 8
// 86.824 us; speedup vs baseline: 1.0775x; 1.0775x over previous
//
#include <hip/hip_runtime.h>

// Chamfer via MFMA v3: no ws table, no pack kernel, no LDS.
// Per wave: 64 fixed F-columns (2 B-frags in registers, built from raw coords);
// stream S-rows as A-frags packed in-register. d2 = sum_k A[k]*B[k], K=16
// hi/lo bf16 split (verified absmax 0.0 in rounds 3/6/7).
// C/D col=lane&31 -> min over streamed rows is a pure register min3-tree;
// one shfl_xor(32) at the end combines the two row-subsets. Partial mins per
// (db, nsplit) go to ws; tiny reduce kernel does min/sqrt/mean/atomicAdd.

typedef __attribute__((ext_vector_type(8)))  short    bf16x8;
typedef __attribute__((ext_vector_type(16))) float    f32x16;
typedef __attribute__((ext_vector_type(4)))  unsigned uint32x4;

constexpr int NPTS   = 8192;
constexpr int NSPLIT = 4;                 // streamed-row split (parallelism)
constexpr int SROWS  = NPTS / NSPLIT;     // 2048 rows per wave
constexpr int STEPS  = SROWS / 32;        // 64 steps

__device__ inline unsigned hi16(float f) { return __float_as_uint(f) & 0xFFFF0000u; }
__device__ inline float   hi16f(float f) { return __uint_as_float(hi16(f)); }
// low16 = bf16(lo_src), high16 = bf16(hi_src)   (1x v_perm_b32)
__device__ inline unsigned pack2(float lo_src, float hi_src) {
    return __builtin_amdgcn_perm(__float_as_uint(hi_src),
                                 __float_as_uint(lo_src), 0x07060302u);
}

__global__ __launch_bounds__(256, 4) void chamfer_v3(
    const float* __restrict__ pred, const float* __restrict__ targ,
    float* __restrict__ part) {
    const int lane = threadIdx.x & 63;
    const int wv   = threadIdx.x >> 6;
    const int l31  = lane & 31;
    const int g    = lane >> 5;           // k-group (0: k0-7, 1: k8-15)
    const int mg   = blockIdx.x * 4 + wv; // 0..127 column group (64 cols)
    const int ns   = blockIdx.y;          // 0..NSPLIT-1
    const int db   = blockIdx.z;          // dir = db&1, b = db>>1
    const int dir  = db & 1, b = db >> 1;

    // dir0: for each PRED point, min over TARG  -> F = pred (cols), S = targ.
    const float* F = (dir ? targ : pred) + (size_t)b * 3 * NPTS;
    const float* S = (dir ? pred : targ) + (size_t)b * 3 * NPTS;

    const unsigned ONE2 = 0x3F803F80u;    // bf16 1.0 | 1.0

    // B k-scheme: [1,1,t2h,t2l,xh,xl,xh,yh | yl,yh,zh,zl,zh,0,0,0]
    auto build_bf = [&](int m) -> bf16x8 {
        float x = F[m], y = F[NPTS + m], z = F[2 * NPTS + m];
        float t2 = fmaf(x, x, fmaf(y, y, z * z));
        float t2l = t2 - hi16f(t2);
        float xl  = x  - hi16f(x);
        float yl  = y  - hi16f(y);
        float zl  = z  - hi16f(z);
        uint32x4 d;
        if (g == 0) {
            d[0] = ONE2;
            d[1] = pack2(t2, t2l);
            d[2] = pack2(x, xl);
            d[3] = pack2(x, y);
        } else {
            d[0] = pack2(yl, y);
            d[1] = pack2(z, zl);
            d[2] = pack2(zl, 0.f);
            d[2] = pack2(z, zl);                 // placeholder (fixed below)
            d[0] = pack2(yl, y);
            d[1] = pack2(z, zl);
            d[2] = pack2(zl == zl ? zl : zl, 0.f); // zh? see corrected below
            d[3] = 0u;
            // corrected explicit build:
            d[0] = pack2(yl, y);                 // yl | yh
            d[1] = pack2(z, zl);                 // zh | zl
            d[2] = pack2(z, 0.f);                // zh | 0
            d[3] = 0u;                           // 0 | 0
        }
        return __builtin_bit_cast(bf16x8, d);
    };

    const int m0 = mg * 64 + l31;
    bf16x8 bf0 = build_bf(m0);
    bf16x8 bf1 = build_bf(m0 + 32);

    // A k-scheme: [p2h,p2l,1,1,mxh,mxh,mxl,myh | myh,myl,mzh,mzh,mzl,0,0,0]
    auto build_af = [&](float x, float y, float z) -> bf16x8 {
        float mx = -2.f * x, my = -2.f * y, mz = -2.f * z;
        uint32x4 d;
        if (g == 0) {
            float p2  = fmaf(x, x, fmaf(y, y, z * z));
            float p2l = p2 - hi16f(p2);
            float mxl = mx - hi16f(mx);
            d[0] = pack2(p2, p2l);               // p2h | p2l
            d[1] = ONE2;                         // 1 | 1
            d[2] = pack2(mx, mx);                // mxh | mxh
            d[3] = pack2(mxl, my);               // mxl | myh
        } else {
            float myl = my - hi16f(my);
            float mzl = mz - hi16f(mz);
            d[0] = pack2(my, myl);               // myh | myl
            d[1] = pack2(mz, mz);                // mzh | mzh
            d[2] = pack2(mzl, 0.f);              // mzl | 0
            d[3] = 0u;                           // 0 | 0
        }
        return __builtin_bit_cast(bf16x8, d);
    };

    f32x16 zero;
    #pragma unroll
    for (int i = 0; i < 16; ++i) zero[i] = 0.f;

    const float INF = __int_as_float(0x7F800000);
    float acc0 = INF, acc1 = INF;

    auto tree = [&](float acc, const f32x16& c) -> float {
        float t0 = fminf(fminf(c[0],  c[1]),  c[2]);
        float t1 = fminf(fminf(c[3],  c[4]),  c[5]);
        float t2 = fminf(fminf(c[6],  c[7]),  c[8]);
        float t3 = fminf(fminf(c[9],  c[10]), c[11]);
        float t4 = fminf(fminf(c[12], c[13]), c[14]);
        float r0 = fminf(fminf(t0, t1), t2);
        float r1 = fminf(fminf(t3, t4), c[15]);
        return fminf(fminf(r0, r1), acc);
    };

    const float* Sx = S + (size_t)ns * SROWS + l31;
    float cx = Sx[0], cy = Sx[NPTS], cz = Sx[2 * NPTS];
    for (int s = 0; s < STEPS; ++s) {
        float nx = 0.f, ny = 0.f, nz = 0.f;
        if (s + 1 < STEPS) {
            int o = (s + 1) * 32;
            nx = Sx[o]; ny = Sx[o + NPTS]; nz = Sx[o + 2 * NPTS];
        }
        bf16x8 af = build_af(cx, cy, cz);
        f32x16 c0 = __builtin_amdgcn_mfma_f32_32x32x16_bf16(af, bf0, zero, 0, 0, 0);
        f32x16 c1 = __builtin_amdgcn_mfma_f32_32x32x16_bf16(af, bf1, zero, 0, 0, 0);
        acc0 = tree(acc0, c0);
        acc1 = tree(acc1, c1);
        cx = nx; cy = ny; cz = nz;
    }

    // combine the two row-subsets (lane and lane^32 hold same column)
    acc0 = fminf(acc0, __shfl_xor(acc0, 32));
    acc1 = fminf(acc1, __shfl_xor(acc1, 32));

    if (lane < 32) {
        float* dst = part + ((size_t)db * NSPLIT + ns) * NPTS + mg * 64;
        dst[lane]      = acc0;
        dst[32 + lane] = acc1;
    }
}

// min over NSPLIT partials, sqrt, mean, sum both directions
__global__ __launch_bounds__(256) void reduce_k(
    const float* __restrict__ part, float* __restrict__ out) {
    int tid = blockIdx.x * 256 + threadIdx.x;   // 0..65535
    int db  = tid >> 13;
    int m   = tid & (NPTS - 1);
    const float* base = part + (size_t)db * NSPLIT * NPTS + m;
    float v = base[0];
    #pragma unroll
    for (int nsh = 1; nsh < NSPLIT; ++nsh)
        v = fminf(v, base[(size_t)nsh * NPTS]);
    float d = sqrtf(fmaxf(v, 0.f)) * (1.0f / 32768.0f);
    for (int off = 32; off; off >>= 1) d += __shfl_down(d, off);
    __shared__ float wsum[4];
    if ((threadIdx.x & 63) == 0) wsum[threadIdx.x >> 6] = d;
    __syncthreads();
    if (threadIdx.x == 0) atomicAdd(out, wsum[0] + wsum[1] + wsum[2] + wsum[3]);
}

extern "C" void kernel_launch(void* const* d_in, const int* in_sizes, int n_in,
                              void* d_out, int out_size, void* d_ws, size_t ws_size,
                              hipStream_t stream) {
    const float* pred = (const float*)d_in[0];
    const float* targ = (const float*)d_in[1];
    float* out  = (float*)d_out;
    float* part = (float*)d_ws;   // 8 * NSPLIT * NPTS * 4 = 1 MB

    hipMemsetAsync(d_out, 0, sizeof(float), stream);

    dim3 grid(32, NSPLIT, 8);     // 32 x 4 x 8 = 1024 blocks x 4 waves
    chamfer_v3<<<grid, 256, 0, stream>>>(pred, targ, part);

    reduce_k<<<(8 * NPTS) / 256, 256, 0, stream>>>(part, out);
}